// Round 4
// baseline (1562.582 us; speedup 1.0000x reference)
//
#include <hip/hip_runtime.h>

typedef unsigned short u16;
typedef unsigned int   u32;
typedef __bf16 bfx8 __attribute__((ext_vector_type(8)));
typedef float  f32x4 __attribute__((ext_vector_type(4)));

__device__ __forceinline__ float b2f(u16 v) {
    union { u32 u; float f; } c; c.u = ((u32)v) << 16; return c.f;
}
__device__ __forceinline__ u16 f2bf(float f) {
    union { float f; u32 u; } c; c.f = f;
    u32 u = c.u;
    return (u16)((u + 0x7fffu + ((u >> 16) & 1u)) >> 16);  // RNE
}

// ---------------------------------------------------------------------------
// Input dtype detection: bf16 normal data -> nearly all even u16 elements have
// a plausible bf16 exponent; f32 data -> even u16s are mantissa halves
// (uniform bits, ~19% plausible). flag=1 means inputs are f32.
// ---------------------------------------------------------------------------
__global__ void detect_dtype(const u16* __restrict__ x, int* __restrict__ flag)
{
    const int tid = threadIdx.x;
    int cnt = 0;
    for (int i = tid; i < 2048; i += 256) {
        const u16 v = x[2 * i];
        const int e = (v >> 7) & 0xFF;
        if ((v & 0x7fff) == 0 || (e >= 96 && e <= 144)) cnt++;
    }
#pragma unroll
    for (int off = 32; off > 0; off >>= 1) cnt += __shfl_xor(cnt, off);
    __shared__ int sred[4];
    if ((tid & 63) == 0) sred[tid >> 6] = cnt;
    __syncthreads();
    if (tid == 0) {
        const int total = sred[0] + sred[1] + sred[2] + sred[3];
        flag[0] = (total < 1024) ? 1 : 0;
    }
}

// Convert small vector to bf16 (copy if already bf16)
__global__ void to_bf16(const void* __restrict__ in, u16* __restrict__ out,
                        int n, const int* __restrict__ flag)
{
    const int i = blockIdx.x * 256 + threadIdx.x;
    if (i < n)
        out[i] = (*flag) ? f2bf(((const float*)in)[i]) : ((const u16*)in)[i];
}

// ---------------------------------------------------------------------------
// Batched GEMM: C[m][n] = sum_k A[m][k] * Bt[n][k]   (acc f32)
// A may be raw input (f32 or bf16, per aF32 flag); Bt always bf16.
// epi_mode: 1 = store; 2 = (acc+add1)*mul1; 3 = acc+bias+add1
// Store width: f32 if cF32 flag set, else bf16.
// ---------------------------------------------------------------------------
__global__ __launch_bounds__(256, 2)
void gemm_bt(const void* __restrict__ A, const u16* __restrict__ Bt,
             void* __restrict__ C,
             int M, int N, int K, int lda, int ldb, int ldc,
             long sAb, long sAh, long sBb, long sBh, long sCb, long sCh, int nh,
             int epi_mode, const u16* __restrict__ add1, long sAddB, long sAddH,
             int ldadd, const u16* __restrict__ mul1, const u16* __restrict__ bias,
             const int* __restrict__ aF32, const int* __restrict__ cF32)
{
    __shared__ __align__(16) u16 As[128 * 40];
    __shared__ __align__(16) u16 Bs[128 * 40];
    const bool af32 = aF32 && (*aF32 != 0);
    const bool cf32 = cF32 && (*cF32 != 0);
    const int z = blockIdx.z, zb = z / nh, zh = z - zb * nh;
    const long aoff = (long)zb * sAb + (long)zh * sAh;
    Bt += (long)zb * sBb + (long)zh * sBh;
    const long coff = (long)zb * sCb + (long)zh * sCh;
    const int m0 = blockIdx.x * 128, n0 = blockIdx.y * 128;
    const int tid = threadIdx.x, lane = tid & 63, wave = tid >> 6;
    const int wm = (wave >> 1) * 64, wn = (wave & 1) * 64;
    const int q = lane >> 4, l16 = lane & 15;
    const int rowL = tid >> 2, kcol = (tid & 3) * 8;

    f32x4 acc[4][4] = {};

    for (int k0 = 0; k0 < K; k0 += 32) {
#pragma unroll
        for (int p = 0; p < 2; ++p) {
            const int r = rowL + p * 64;
            uint4 va = {0, 0, 0, 0}, vb = {0, 0, 0, 0};
            if (m0 + r < M) {
                const long ai = aoff + (long)(m0 + r) * lda + k0 + kcol;
                if (af32) {
                    const float* Af = (const float*)A + ai;
                    float4 f0 = *(const float4*)Af;
                    float4 f1 = *(const float4*)(Af + 4);
                    u16* u = (u16*)&va;
                    u[0] = f2bf(f0.x); u[1] = f2bf(f0.y);
                    u[2] = f2bf(f0.z); u[3] = f2bf(f0.w);
                    u[4] = f2bf(f1.x); u[5] = f2bf(f1.y);
                    u[6] = f2bf(f1.z); u[7] = f2bf(f1.w);
                } else {
                    va = *(const uint4*)((const u16*)A + ai);
                }
            }
            if (n0 + r < N) vb = *(const uint4*)(Bt + (long)(n0 + r) * ldb + k0 + kcol);
            *(uint4*)(&As[r * 40 + kcol]) = va;
            *(uint4*)(&Bs[r * 40 + kcol]) = vb;
        }
        __syncthreads();
        bfx8 af[4], bfr[4];
#pragma unroll
        for (int t = 0; t < 4; ++t) {
            af[t]  = *(const bfx8*)(&As[(wm + t * 16 + l16) * 40 + q * 8]);
            bfr[t] = *(const bfx8*)(&Bs[(wn + t * 16 + l16) * 40 + q * 8]);
        }
#pragma unroll
        for (int i = 0; i < 4; ++i)
#pragma unroll
            for (int j = 0; j < 4; ++j)
                acc[i][j] = __builtin_amdgcn_mfma_f32_16x16x32_bf16(af[i], bfr[j], acc[i][j], 0, 0, 0);
        __syncthreads();
    }

#pragma unroll
    for (int i = 0; i < 4; ++i) {
#pragma unroll
        for (int j = 0; j < 4; ++j) {
#pragma unroll
            for (int r = 0; r < 4; ++r) {
                const int gm = m0 + wm + i * 16 + q * 4 + r;
                const int gn = n0 + wn + j * 16 + l16;
                if (gm < M && gn < N) {
                    float v = acc[i][j][r];
                    const long cidx = coff + (long)gm * ldc + gn;
                    if (epi_mode == 2) {
                        const long aidx = (long)zb * sAddB + (long)zh * sAddH + (long)gm * ldadd + gn;
                        v = (v + b2f(add1[aidx])) * b2f(mul1[aidx]);
                    } else if (epi_mode == 3) {
                        const long aidx = (long)gm * ldadd + gn;
                        v = v + b2f(bias[gn]) + b2f(add1[aidx]);
                    }
                    if (cf32) ((float*)C)[cidx] = v;
                    else      ((u16*)C)[cidx] = f2bf(v);
                }
            }
        }
    }
}

// ---------------------------------------------------------------------------
// AT-GEMM: C[i][j] = sum_n A[n][i] * B[n][j]  (contract rows; ws bf16 in, f32 out)
// ---------------------------------------------------------------------------
__global__ __launch_bounds__(256, 2)
void gemm_at(const u16* __restrict__ A, const u16* __restrict__ B,
             float* __restrict__ C,
             int M, int N, int K, int lda, int ldb, int ldc,
             long sAb, long sAh, long sBb, long sBh, long sCb, long sCh, int nh)
{
    __shared__ __align__(16) u16 At[128 * 72];
    __shared__ __align__(16) u16 Bl[128 * 72];
    const int z = blockIdx.z, zb = z / nh, zh = z - zb * nh;
    A += (long)zb * sAb + (long)zh * sAh;
    B += (long)zb * sBb + (long)zh * sBh;
    const long coff = (long)zb * sCb + (long)zh * sCh;
    const int i0 = blockIdx.x * 128, j0 = blockIdx.y * 128;
    const int tid = threadIdx.x, lane = tid & 63, wave = tid >> 6;
    const int wm = (wave >> 1) * 64, wn = (wave & 1) * 64;
    const int q = lane >> 4, l16 = lane & 15;
    const int tr = tid >> 4, tc8 = (tid & 15) * 8;

    f32x4 acc[4][4] = {};

    for (int n0 = 0; n0 < K; n0 += 64) {
#pragma unroll
        for (int p = 0; p < 4; ++p) {
            const int nn = tr + p * 16;
            uint4 va = {0, 0, 0, 0}, vb = {0, 0, 0, 0};
            if (i0 + tc8 < M) va = *(const uint4*)(A + (long)(n0 + nn) * lda + i0 + tc8);
            if (j0 + tc8 < N) vb = *(const uint4*)(B + (long)(n0 + nn) * ldb + j0 + tc8);
            const u16* ua = (const u16*)&va;
            const u16* ub = (const u16*)&vb;
#pragma unroll
            for (int e = 0; e < 8; ++e) {
                At[(tc8 + e) * 72 + nn] = ua[e];
                Bl[(tc8 + e) * 72 + nn] = ub[e];
            }
        }
        __syncthreads();
#pragma unroll
        for (int ks = 0; ks < 2; ++ks) {
            bfx8 af[4], bfr[4];
#pragma unroll
            for (int t = 0; t < 4; ++t) {
                af[t]  = *(const bfx8*)(&At[(wm + t * 16 + l16) * 72 + ks * 32 + q * 8]);
                bfr[t] = *(const bfx8*)(&Bl[(wn + t * 16 + l16) * 72 + ks * 32 + q * 8]);
            }
#pragma unroll
            for (int i = 0; i < 4; ++i)
#pragma unroll
                for (int j = 0; j < 4; ++j)
                    acc[i][j] = __builtin_amdgcn_mfma_f32_16x16x32_bf16(af[i], bfr[j], acc[i][j], 0, 0, 0);
        }
        __syncthreads();
    }

#pragma unroll
    for (int i = 0; i < 4; ++i)
#pragma unroll
        for (int j = 0; j < 4; ++j)
#pragma unroll
            for (int r = 0; r < 4; ++r) {
                const int gm = i0 + wm + i * 16 + q * 4 + r;
                const int gn = j0 + wn + j * 16 + l16;
                if (gm < M && gn < N)
                    C[coff + (long)gm * ldc + gn] = acc[i][j][r];
            }
}

// ---------------------------------------------------------------------------
// Tiled 512x512 transpose of a raw-input weight (f32 or bf16 per flag) -> bf16
// ---------------------------------------------------------------------------
__global__ void transpose_k(const void* __restrict__ in, u16* __restrict__ out,
                            const int* __restrict__ dflag)
{
    __shared__ __align__(16) u16 tile[64 * 72];
    const bool f32 = (*dflag != 0);
    const int r0 = blockIdx.x * 64, c0 = blockIdx.y * 64;
    const int tid = threadIdx.x;
    {
        const int tr = tid >> 3, tc = (tid & 7) * 8;
#pragma unroll
        for (int p = 0; p < 2; ++p) {
            const int r = tr + p * 32;
            const long base = (long)(r0 + r) * 512 + c0 + tc;
#pragma unroll
            for (int e = 0; e < 8; ++e) {
                tile[r * 72 + tc + e] = f32 ? f2bf(((const float*)in)[base + e])
                                            : ((const u16*)in)[base + e];
            }
        }
    }
    __syncthreads();
    {
        const int oc = tid >> 3, rn = (tid & 7) * 8;
#pragma unroll
        for (int p = 0; p < 2; ++p) {
            const int c = oc + p * 32;
            u16 res[8];
#pragma unroll
            for (int i = 0; i < 8; ++i) res[i] = tile[(rn + i) * 72 + c];
            *(uint4*)(out + (long)(c0 + c) * 512 + r0 + rn) = *(uint4*)res;
        }
    }
}

// LayerNorm row stats over 512 channels (ws bf16 input)
__global__ void ln_stats(const u16* __restrict__ in, float* __restrict__ mu,
                         float* __restrict__ rstd)
{
    const long row = blockIdx.x;
    const u16* p = in + row * 512;
    const int tid = threadIdx.x;
    const float v0 = b2f(p[tid * 2]), v1 = b2f(p[tid * 2 + 1]);
    float s = v0 + v1, sq = v0 * v0 + v1 * v1;
#pragma unroll
    for (int off = 32; off > 0; off >>= 1) {
        s  += __shfl_xor(s, off);
        sq += __shfl_xor(sq, off);
    }
    __shared__ float ls[4], lq[4];
    if ((tid & 63) == 0) { ls[tid >> 6] = s; lq[tid >> 6] = sq; }
    __syncthreads();
    if (tid == 0) {
        s = ls[0] + ls[1] + ls[2] + ls[3];
        sq = lq[0] + lq[1] + lq[2] + lq[3];
        const float m = s * (1.0f / 512.0f);
        float var = sq * (1.0f / 512.0f) - m * m;
        var = fmaxf(var, 0.0f);
        mu[row] = m;
        rstd[row] = rsqrtf(var + 1e-5f);
    }
}

// Apply LN in place on ws bf16
__global__ void ln_apply(u16* __restrict__ x, const float* __restrict__ mu,
                         const float* __restrict__ rstd,
                         const u16* __restrict__ g, const u16* __restrict__ b)
{
    const long idx = (long)blockIdx.x * 256 + threadIdx.x;
    const long row = idx >> 6;
    const int  c8  = (int)(idx & 63) * 8;
    u16* p = x + row * 512 + c8;
    uint4 v = *(uint4*)p;
    u16* u = (u16*)&v;
    const float m_ = mu[row], rs = rstd[row];
#pragma unroll
    for (int i = 0; i < 8; ++i)
        u[i] = f2bf((b2f(u[i]) - m_) * rs * b2f(g[c8 + i]) + b2f(b[c8 + i]));
    *(uint4*)p = v;
}

__global__ void zero_f32(float* __restrict__ p, int n)
{
    const int i = blockIdx.x * 256 + threadIdx.x;
    if (i < n) p[i] = 0.0f;
}

// Column sum-of-squares over n of ws-bf16 (B,4096,512), chunked + atomic
__global__ void colssq(const u16* __restrict__ in, float* __restrict__ ssq, int rowsPerChunk)
{
    const int b = blockIdx.x, cchunk = blockIdx.y, nchunk = blockIdx.z;
    const int c = cchunk * 256 + threadIdx.x;
    const u16* p = in + (long)b * 4096 * 512 + (long)nchunk * rowsPerChunk * 512 + c;
    float acc = 0.f;
    for (int n = 0; n < rowsPerChunk; ++n) {
        const float v = b2f(p[(long)n * 512]);
        acc += v * v;
    }
    atomicAdd(&ssq[b * 512 + c], acc);
}

// Row softmax over 512 (1/sqrt(512) pre-scale), f32 in -> bf16 out
__global__ void softmax_ab(const float* __restrict__ Ab, u16* __restrict__ out)
{
    const long row = blockIdx.x;
    const float* p = Ab + row * 512;
    const int tid = threadIdx.x;
    const float scale = 0.044194173824159216f;  // 1/sqrt(512)
    const float a = p[tid] * scale, b = p[tid + 256] * scale;
    float m = fmaxf(a, b);
#pragma unroll
    for (int off = 32; off > 0; off >>= 1) m = fmaxf(m, __shfl_xor(m, off));
    __shared__ float red[8];
    if ((tid & 63) == 0) red[tid >> 6] = m;
    __syncthreads();
    m = fmaxf(fmaxf(red[0], red[1]), fmaxf(red[2], red[3]));
    const float e0 = __expf(a - m), e1 = __expf(b - m);
    float s = e0 + e1;
#pragma unroll
    for (int off = 32; off > 0; off >>= 1) s += __shfl_xor(s, off);
    if ((tid & 63) == 0) red[4 + (tid >> 6)] = s;
    __syncthreads();
    s = red[4] + red[5] + red[6] + red[7];
    const float inv = 1.0f / fmaxf(s, 1e-30f);
    out[row * 512 + tid]       = f2bf(e0 * inv);
    out[row * 512 + tid + 256] = f2bf(e1 * inv);
}

// Row softmax over 64; logits = G[d][e]*rescale[h]/(||k_d||*||q_e||). Row=z*64+d.
__global__ void softmax_g(const float* __restrict__ G, const u16* __restrict__ rescale,
                          const float* __restrict__ ssq_k, const float* __restrict__ ssq_q,
                          u16* __restrict__ out)
{
    const int row = blockIdx.x * 4 + (threadIdx.x >> 6);
    const int lane = threadIdx.x & 63;
    const int zz = row >> 6, d = row & 63;
    const int b_ = zz >> 3, h = zz & 7;
    const float rk = 1.0f / fmaxf(sqrtf(fmaxf(ssq_k[b_ * 512 + h * 64 + d], 0.f)), 1e-12f);
    const float rq = 1.0f / fmaxf(sqrtf(fmaxf(ssq_q[b_ * 512 + h * 64 + lane], 0.f)), 1e-12f);
    const float v = G[(long)row * 64 + lane] * rk * rq * b2f(rescale[h]);
    float m = v;
#pragma unroll
    for (int off = 32; off > 0; off >>= 1) m = fmaxf(m, __shfl_xor(m, off));
    const float e = __expf(v - m);
    float s = e;
#pragma unroll
    for (int off = 32; off > 0; off >>= 1) s += __shfl_xor(s, off);
    out[(long)row * 64 + lane] = f2bf(e / fmaxf(s, 1e-30f));
}

// Depthwise 3x3 SAME conv on NHWC (B,64,64,512) ws bf16, optional exact GeLU.
__global__ void dwconv3x3(const u16* __restrict__ in, const u16* __restrict__ w,
                          u16* __restrict__ out, int do_gelu)
{
    __shared__ u16 wl[4608];
    const int tid = threadIdx.x;
    for (int i = tid; i < 4608; i += 256) wl[i] = w[i];
    __syncthreads();
    const int b = blockIdx.x >> 6, y = blockIdx.x & 63;
    const long base = (long)b * 64 * 64 * 512;
    for (int t = 0; t < 16; ++t) {
        const int idx = t * 256 + tid;
        const int cg = idx & 63, x = idx >> 6;
        float acc[8] = {};
#pragma unroll
        for (int dy = -1; dy <= 1; ++dy) {
            const int yy = y + dy;
            if (yy < 0 || yy > 63) continue;
#pragma unroll
            for (int dx = -1; dx <= 1; ++dx) {
                const int xx = x + dx;
                if (xx < 0 || xx > 63) continue;
                const uint4 v = *(const uint4*)(in + base + ((long)yy * 64 + xx) * 512 + cg * 8);
                const u16* u = (const u16*)&v;
                const int wo = (dy + 1) * 3 + (dx + 1);
#pragma unroll
                for (int i = 0; i < 8; ++i)
                    acc[i] += b2f(u[i]) * b2f(wl[(cg * 8 + i) * 9 + wo]);
            }
        }
        u16 res[8];
#pragma unroll
        for (int i = 0; i < 8; ++i) {
            float v = acc[i];
            if (do_gelu) v = 0.5f * v * (1.0f + erff(v * 0.70710678118654752f));
            res[i] = f2bf(v);
        }
        *(uint4*)(out + base + ((long)y * 64 + x) * 512 + cg * 8) = *(uint4*)res;
    }
}

// ---------------------------------------------------------------------------
extern "C" void kernel_launch(void* const* d_in, const int* in_sizes, int n_in,
                              void* d_out, int out_size, void* d_ws, size_t ws_size,
                              hipStream_t stream)
{
    const void* x     = d_in[0];
    const void* illu  = d_in[1];
    const void* sem   = d_in[2];
    const void* WkS   = d_in[3];
    const void* WqS   = d_in[4];
    const void* WvS   = d_in[5];
    const void* ln_g  = d_in[6];
    const void* ln_b  = d_in[7];
    const void* Wq    = d_in[8];
    const void* Wk    = d_in[9];
    const void* Wv    = d_in[10];
    const void* resc  = d_in[11];
    const void* projW = d_in[12];
    const void* projB = d_in[13];
    const void* dw1   = d_in[14];
    const void* dw2   = d_in[15];
    (void)in_sizes; (void)n_in; (void)out_size; (void)ws_size;

    char* ws = (char*)d_ws;
    size_t off = 0;
    auto nxt = [&](size_t bytes) -> void* {
        void* p = ws + off;
        off += (bytes + 255) & ~(size_t)255;
        return p;
    };

    // Workspace ~119 MB
    u16* WqT   = (u16*)nxt(524288);
    u16* WkT   = (u16*)nxt(524288);
    u16* WvT   = (u16*)nxt(524288);
    u16* WkST  = (u16*)nxt(524288);
    u16* WqST  = (u16*)nxt(524288);
    u16* WvST  = (u16*)nxt(524288);
    u16* projT = (u16*)nxt(524288);
    u16* A = (u16*)nxt(33554432);   // 3 reusable 33.5MB slots
    u16* B = (u16*)nxt(33554432);
    u16* C = (u16*)nxt(33554432);
    float* Abf  = (float*)nxt(8388608);
    u16*   Absm = (u16*)nxt(4194304);
    float* mu   = (float*)nxt(131072);
    float* rs   = (float*)nxt(131072);
    float* ssq_q = (float*)nxt(16384);
    float* ssq_k = (float*)nxt(16384);
    float* Gf   = (float*)nxt(1048576);
    u16*   attn = (u16*)nxt(524288);
    int*   dflag = (int*)nxt(256);
    u16* ln_gc  = (u16*)nxt(1024);
    u16* ln_bc  = (u16*)nxt(1024);
    u16* projBc = (u16*)nxt(1024);
    u16* rescc  = (u16*)nxt(256);
    u16* dw1c   = (u16*)nxt(9216);
    u16* dw2c   = (u16*)nxt(9216);

    const dim3 blk(256);

    // --- dtype detection + small-vector conversion -----------------------
    detect_dtype<<<dim3(1), blk, 0, stream>>>((const u16*)x, dflag);
    to_bf16<<<dim3(2), blk, 0, stream>>>(ln_g,  ln_gc,  512,  dflag);
    to_bf16<<<dim3(2), blk, 0, stream>>>(ln_b,  ln_bc,  512,  dflag);
    to_bf16<<<dim3(2), blk, 0, stream>>>(projB, projBc, 512,  dflag);
    to_bf16<<<dim3(1), blk, 0, stream>>>(resc,  rescc,  8,    dflag);
    to_bf16<<<dim3(18), blk, 0, stream>>>(dw1,  dw1c,   4608, dflag);
    to_bf16<<<dim3(18), blk, 0, stream>>>(dw2,  dw2c,   4608, dflag);

    auto wT = [&](const void* w, u16* o) {
        transpose_k<<<dim3(8, 8, 1), blk, 0, stream>>>(w, o, dflag);
    };
    wT(Wq, WqT); wT(Wk, WkT); wT(Wv, WvT);
    wT(WkS, WkST); wT(WqS, WqST); wT(WvS, WvST); wT(projW, projT);

    auto gemm = [&](const void* Ap, const u16* Btp, void* Cp, int M, int N, int K,
                    int lda, int ldb, int ldc, int nz, int nh,
                    long sAb, long sAh, long sBb, long sBh, long sCb, long sCh,
                    int epi, const u16* add1, long sAddB, long sAddH, int ldadd,
                    const u16* mul1, const u16* bias,
                    const int* aF32, const int* cF32) {
        dim3 g((M + 127) / 128, (N + 127) / 128, nz);
        gemm_bt<<<g, blk, 0, stream>>>(Ap, Btp, Cp, M, N, K, lda, ldb, ldc,
            sAb, sAh, sBb, sBh, sCb, sCh, nh, epi, add1, sAddB, sAddH, ldadd,
            mul1, bias, aF32, cF32);
    };

    // --- SIF channel attention -------------------------------------------
    gemm(illu, WkST, A, 32768, 512, 512, 512, 512, 512, 1, 1, 0,0,0,0,0,0, 1,
         nullptr,0,0,0, nullptr, nullptr, dflag, nullptr);
    ln_stats<<<dim3(32768), blk, 0, stream>>>(A, mu, rs);
    ln_apply<<<dim3(8192), blk, 0, stream>>>(A, mu, rs, ln_gc, ln_bc);
    gemm(sem, WqST, B, 32768, 512, 512, 512, 512, 512, 1, 1, 0,0,0,0,0,0, 1,
         nullptr,0,0,0, nullptr, nullptr, dflag, nullptr);
    ln_stats<<<dim3(32768), blk, 0, stream>>>(B, mu, rs);
    ln_apply<<<dim3(8192), blk, 0, stream>>>(B, mu, rs, ln_gc, ln_bc);
    // Ab[b][i][j] = sum_n Qn[n][i]*Kn[n][j]
    gemm_at<<<dim3(4, 4, 8), blk, 0, stream>>>(B, A, Abf, 512, 512, 4096,
        512, 512, 512, 2097152, 0, 2097152, 0, 262144, 0, 1);
    softmax_ab<<<dim3(4096), blk, 0, stream>>>(Abf, Absm);

    // --- q/k paths + head attention matrix -------------------------------
    gemm(x, WqT, A, 32768, 512, 512, 512, 512, 512, 1, 1, 0,0,0,0,0,0, 1,
         nullptr,0,0,0, nullptr, nullptr, dflag, nullptr);
    zero_f32<<<dim3(16), blk, 0, stream>>>(ssq_q, 4096);
    colssq<<<dim3(8, 2, 16), blk, 0, stream>>>(A, ssq_q, 256);
    gemm(x, WkT, B, 32768, 512, 512, 512, 512, 512, 1, 1, 0,0,0,0,0,0, 1,
         nullptr,0,0,0, nullptr, nullptr, dflag, nullptr);
    zero_f32<<<dim3(16), blk, 0, stream>>>(ssq_k, 4096);
    colssq<<<dim3(8, 2, 16), blk, 0, stream>>>(B, ssq_k, 256);
    // G[z][d][e] = sum_n k_inp[n][h*64+d]*q_inp[n][h*64+e], z=b*8+h
    gemm_at<<<dim3(1, 1, 64), blk, 0, stream>>>(B, A, Gf, 64, 64, 4096,
        512, 512, 64, 2097152, 64, 2097152, 64, 32768, 4096, 8);
    softmax_g<<<dim3(1024), blk, 0, stream>>>(Gf, rescc, ssq_k, ssq_q, attn);

    // --- v path + output --------------------------------------------------
    gemm(x, WvT, A, 32768, 512, 512, 512, 512, 512, 1, 1, 0,0,0,0,0,0, 1,
         nullptr,0,0,0, nullptr, nullptr, dflag, nullptr);
    gemm(illu, WvST, B, 32768, 512, 512, 512, 512, 512, 1, 1, 0,0,0,0,0,0, 1,
         nullptr,0,0,0, nullptr, nullptr, dflag, nullptr);
    // vg = (vsif@Absm^T + vsif) * v_inp -> C
    gemm(B, Absm, C, 4096, 512, 512, 512, 512, 512, 8, 1,
         2097152, 0, 262144, 0, 2097152, 0, 2, B, 2097152, 0, 512, A, nullptr,
         nullptr, nullptr);
    // o[b][n][h*64+d] = sum_e attn[z][d][e]*vg[b][n][h*64+e] -> B
    gemm(C, attn, B, 4096, 64, 64, 512, 64, 512, 64, 8,
         2097152, 64, 32768, 4096, 2097152, 64, 1, nullptr,0,0,0, nullptr, nullptr,
         nullptr, nullptr);
    // positional: p1 = gelu(dw(v_inp)) -> C ; p2 = dw(p1) -> A
    dwconv3x3<<<dim3(512), blk, 0, stream>>>(A, dw1c, C, 1);
    dwconv3x3<<<dim3(512), blk, 0, stream>>>(C, dw2c, A, 0);
    // out = o@proj_w + proj_b + p2 -> d_out (width per dflag)
    gemm(B, projT, d_out, 32768, 512, 512, 512, 512, 512, 1, 1, 0,0,0,0,0,0,
         3, A, 0, 0, 512, nullptr, projBc, nullptr, dflag);
}